// Round 2
// baseline (81.166 us; speedup 1.0000x reference)
//
#include <hip/hip_runtime.h>

#define HW    256
#define TW    32                  // tile width
#define TH    16                  // tile height
#define HALO  3
#define PROWS (TH + 2*HALO)       // 22 halo rows
#define PCOLS (TW + 2*HALO)       // 38 halo cols
#define LSTRIDE (PCOLS + 2)       // 40 -> only 2-way lane aliasing (free)

__global__ __launch_bounds__(256) void census_loss_kernel(
    const float* __restrict__ x, const float* __restrict__ y,
    float* __restrict__ out)
{
    __shared__ float sgx[PROWS][LSTRIDE];
    __shared__ float sgy[PROWS][LSTRIDE];

    const int b   = blockIdx.z;
    const int ti0 = blockIdx.y * TH;     // tile row origin
    const int tj0 = blockIdx.x * TW;     // tile col origin

    const float* xb = x + (size_t)b * 3 * HW * HW;
    const float* yb = y + (size_t)b * 3 * HW * HW;

    const int tid = threadIdx.x;
    const float third = 1.0f / 3.0f;

    // ---- stage grayscale halo (22x38) for both images into LDS ----
    for (int li = tid; li < PROWS * PCOLS; li += 256) {
        int r = li / PCOLS;
        int c = li - r * PCOLS;
        int gi = ti0 + r - HALO;
        int gj = tj0 + c - HALO;
        float gx = 0.0f, gy = 0.0f;
        if ((unsigned)gi < HW && (unsigned)gj < HW) {
            int o = gi * HW + gj;
            gx = (xb[o] + xb[o + HW*HW] + xb[o + 2*HW*HW]) * third;
            gy = (yb[o] + yb[o + HW*HW] + yb[o + 2*HW*HW]) * third;
        }
        sgx[r][c] = gx;
        sgy[r][c] = gy;
    }
    __syncthreads();

    // ---- each thread: column tx, two consecutive rows (2*ty, 2*ty+1) ----
    const int tx = tid & 31;        // 0..31
    const int ty = tid >> 5;        // 0..7
    const int lr0 = 2 * ty;         // local pixel row 0 (halo row lr0+3)
    const int gi0 = ti0 + lr0;
    const int gj  = tj0 + tx;

    const float cx0 = sgx[lr0 + 3][tx + 3];
    const float cy0 = sgy[lr0 + 3][tx + 3];
    const float cx1 = sgx[lr0 + 4][tx + 3];
    const float cy1 = sgy[lr0 + 4][tx + 3];

    float acc0 = 0.0f, acc1 = 0.0f;

    // window rows for both pixels: halo rows lr0 .. lr0+7 (8 rows)
    // row r (0..7): contributes to pixel0 if r<=6, to pixel1 if r>=1
    #pragma unroll
    for (int r = 0; r < 8; ++r) {
        float nx[7], ny[7];
        #pragma unroll
        for (int dx = 0; dx < 7; ++dx) {
            nx[dx] = sgx[lr0 + r][tx + dx];
            ny[dx] = sgy[lr0 + r][tx + dx];
        }
        #pragma unroll
        for (int dx = 0; dx < 7; ++dx) {
            if (r <= 6) {
                float ux = nx[dx] - cx0;
                float uy = ny[dx] - cy0;
                float fx = ux * __builtin_amdgcn_rsqf(0.81f + ux * ux);
                float fy = uy * __builtin_amdgcn_rsqf(0.81f + uy * uy);
                float d  = fx - fy;
                float d2 = d * d;
                acc0 += d2 * __builtin_amdgcn_rcpf(0.1f + d2);
            }
            if (r >= 1) {
                float ux = nx[dx] - cx1;
                float uy = ny[dx] - cy1;
                float fx = ux * __builtin_amdgcn_rsqf(0.81f + ux * ux);
                float fy = uy * __builtin_amdgcn_rsqf(0.81f + uy * uy);
                float d  = fx - fy;
                float d2 = d * d;
                acc1 += d2 * __builtin_amdgcn_rcpf(0.1f + d2);
            }
        }
    }

    // ---- branch-free interior mask (pad=3 border contributes 0) ----
    const bool colv = (gj >= HALO) && (gj < HW - HALO);
    const bool v0 = colv && (gi0     >= HALO) && (gi0     < HW - HALO);
    const bool v1 = colv && (gi0 + 1 >= HALO) && (gi0 + 1 < HW - HALO);
    float acc = (v0 ? acc0 : 0.0f) + (v1 ? acc1 : 0.0f);

    // ---- reduce: wave shuffle -> LDS -> one atomic per block ----
    #pragma unroll
    for (int off = 32; off > 0; off >>= 1)
        acc += __shfl_down(acc, off, 64);

    __shared__ float wsum[4];
    const int lane = tid & 63;
    const int wid  = tid >> 6;
    if (lane == 0) wsum[wid] = acc;
    __syncthreads();
    if (tid == 0) {
        float s = wsum[0] + wsum[1] + wsum[2] + wsum[3];
        const float scale = 1.0f / (49.0f * 8.0f * 256.0f * 256.0f);
        atomicAdd(out, s * scale);
    }
}

extern "C" void kernel_launch(void* const* d_in, const int* in_sizes, int n_in,
                              void* d_out, int out_size, void* d_ws, size_t ws_size,
                              hipStream_t stream) {
    const float* x = (const float*)d_in[0];
    const float* y = (const float*)d_in[1];
    float* out = (float*)d_out;

    // d_out is poisoned to 0xAA before every timed launch -> zero it ourselves
    hipMemsetAsync(out, 0, sizeof(float) * out_size, stream);

    dim3 grid(HW / TW, HW / TH, 8);   // 8 x 16 x 8 = 1024 blocks
    dim3 block(256);
    census_loss_kernel<<<grid, block, 0, stream>>>(x, y, out);
}